// Round 14
// baseline (311.435 us; speedup 1.0000x reference)
//
#include <hip/hip_runtime.h>
#include <hip/hip_fp16.h>

#define NUM_NODES 100000
#define EMB_DIM   64
#define NUM_LAYERS 3
#define NUM_EDGES 3200000
#define NUM_QUERY 1000000

#define BSHIFT   6
#define BNODES   64                                    // nodes per bucket
#define NBUCKETS ((NUM_NODES + BNODES - 1) / BNODES)   // 1563
#define HALF1    782                                   // bucket split point
#define SRC_MASK 131071                                // 17 bits (NUM_NODES < 2^17)
#define NCHUNK   256
#define CHUNK    (NUM_EDGES / NCHUNK)                  // 12500 edges per chunk
#define CHUNK4   (CHUNK / 4)                           // 3125 int4 per chunk

// __half2 <-> u32 bit bridges for nontemporal builtins
__device__ __forceinline__ __half2 u32_as_h2(unsigned u) {
    __half2 h;
    __builtin_memcpy(&h, &u, 4);
    return h;
}
__device__ __forceinline__ unsigned h2_as_u32(__half2 h) {
    unsigned u;
    __builtin_memcpy(&u, &h, 4);
    return u;
}

// ---------------------------------------------------------------------------
// Pass 1: per-chunk bucket histogram in LDS -> hist_g[chunk][bucket]
__global__ __launch_bounds__(256) void chist_kernel(const int* __restrict__ keys,
                                                    int* __restrict__ hist_g) {
    __shared__ int h[NBUCKETS];
    int b = blockIdx.x, tid = threadIdx.x;
    for (int k = tid; k < NBUCKETS; k += 256) h[k] = 0;
    __syncthreads();
    const int4* k4 = (const int4*)(keys + b * CHUNK);
    for (int i = tid; i < CHUNK4; i += 256) {
        int4 d = k4[i];
        atomicAdd(&h[d.x >> BSHIFT], 1);
        atomicAdd(&h[d.y >> BSHIFT], 1);
        atomicAdd(&h[d.z >> BSHIFT], 1);
        atomicAdd(&h[d.w >> BSHIFT], 1);
    }
    __syncthreads();
    for (int k = tid; k < NBUCKETS; k += 256)
        hist_g[b * NBUCKETS + k] = h[k];
}

// Per-bucket exclusive scan across the 256 chunks (one wave per bucket, 4/lane).
__global__ void bscan_kernel(int* __restrict__ hist_g, int* __restrict__ bcnt) {
    int gw   = (blockIdx.x * blockDim.x + threadIdx.x) >> 6;
    int lane = threadIdx.x & 63;
    if (gw >= NBUCKETS) return;
    int v0 = hist_g[(4 * lane + 0) * NBUCKETS + gw];
    int v1 = hist_g[(4 * lane + 1) * NBUCKETS + gw];
    int v2 = hist_g[(4 * lane + 2) * NBUCKETS + gw];
    int v3 = hist_g[(4 * lane + 3) * NBUCKETS + gw];
    int quad = v0 + v1 + v2 + v3, x = quad;
    #pragma unroll
    for (int d = 1; d < 64; d <<= 1) {
        int y = __shfl_up(x, d);
        if (lane >= d) x += y;
    }
    int ex = x - quad;                    // exclusive prefix over chunks
    hist_g[(4 * lane + 0) * NBUCKETS + gw] = ex;
    hist_g[(4 * lane + 1) * NBUCKETS + gw] = ex + v0;
    hist_g[(4 * lane + 2) * NBUCKETS + gw] = ex + v0 + v1;
    hist_g[(4 * lane + 3) * NBUCKETS + gw] = ex + v0 + v1 + v2;
    if (lane == 63) bcnt[gw] = x;         // bucket total
}

// single-block scan over NBUCKETS (2 tiles): boffs[b+1] = inclusive sum
__global__ void scan_kernel(const int* __restrict__ bcnt, int* __restrict__ boffs) {
    __shared__ int tile[1024];
    __shared__ int carry;
    int t = threadIdx.x;
    if (t == 0) { carry = 0; boffs[0] = 0; }
    __syncthreads();
    for (int base = 0; base < NBUCKETS; base += 1024) {
        int v = (base + t < NBUCKETS) ? bcnt[base + t] : 0;
        tile[t] = v;
        __syncthreads();
        for (int d = 1; d < 1024; d <<= 1) {
            int add = (t >= d) ? tile[t - d] : 0;
            __syncthreads();
            tile[t] += add;
            __syncthreads();
        }
        int inc = tile[t] + carry;
        if (base + t < NBUCKETS) boffs[base + t + 1] = inc;
        __syncthreads();
        if (t == 1023) carry = inc;
        __syncthreads();
    }
}

// Pass 2: scatter via LDS cursors. 2 blocks per chunk, split by bucket range —
// every (chunk,bucket) segment still has exactly one writer block.
__global__ __launch_bounds__(256) void cscatter_kernel(
        const int* __restrict__ src, const int* __restrict__ dst,
        const int* __restrict__ boffs, const int* __restrict__ hist_g,
        int* __restrict__ packed) {
    __shared__ int cur[NBUCKETS];
    int b = blockIdx.x >> 1, half = blockIdx.x & 1;
    int LO = half ? HALF1 : 0;
    int HI = half ? NBUCKETS : HALF1;
    int tid = threadIdx.x;
    for (int k = tid; k < NBUCKETS; k += 256)
        cur[k] = boffs[k] + hist_g[b * NBUCKETS + k];
    __syncthreads();
    const int4* s4 = (const int4*)(src + b * CHUNK);
    const int4* d4 = (const int4*)(dst + b * CHUNK);
    for (int i = tid; i < CHUNK4; i += 256) {
        int4 s = s4[i];
        int4 d = d4[i];
        int bk;
        bk = d.x >> BSHIFT;
        if (bk >= LO && bk < HI) { int p = atomicAdd(&cur[bk], 1); packed[p] = s.x | ((d.x & 63) << 17); }
        bk = d.y >> BSHIFT;
        if (bk >= LO && bk < HI) { int p = atomicAdd(&cur[bk], 1); packed[p] = s.y | ((d.y & 63) << 17); }
        bk = d.z >> BSHIFT;
        if (bk >= LO && bk < HI) { int p = atomicAdd(&cur[bk], 1); packed[p] = s.z | ((d.z & 63) << 17); }
        bk = d.w >> BSHIFT;
        if (bk >= LO && bk < HI) { int p = atomicAdd(&cur[bk], 1); packed[p] = s.w | ((d.w & 63) << 17); }
    }
}

// per-bucket local counting sort -> exact per-node CSR (src_srt, offs) + dis
__global__ __launch_bounds__(256) void lsort_kernel(
        const int* __restrict__ boffs, const int* __restrict__ packed,
        int* __restrict__ offs, int* __restrict__ src_srt, float* __restrict__ dis) {
    __shared__ int cnt[BNODES];
    int b   = blockIdx.x;
    int tid = threadIdx.x;
    int beg = boffs[b];
    int end = boffs[b + 1];
    if (tid < BNODES) cnt[tid] = 0;
    __syncthreads();
    for (int i = beg + tid; i < end; i += 256)
        atomicAdd(&cnt[(packed[i] >> 17) & 63], 1);
    __syncthreads();
    if (tid < 64) {                      // wave 0: exclusive scan of 64 counters
        int v = cnt[tid];
        int x = v;
        #pragma unroll
        for (int d = 1; d < 64; d <<= 1) {
            int y = __shfl_up(x, d);
            if (tid >= d) x += y;
        }
        int ex = x - v;                  // exclusive prefix
        int node = (b << BSHIFT) + tid;
        if (node <= NUM_NODES) offs[node] = beg + ex;   // bucket 1562/tid 32 writes offs[N]=E
        if (node <  NUM_NODES) dis[node] = (v > 0) ? rsqrtf((float)v) : 0.0f;
        cnt[tid] = ex;                   // reuse as local cursor
    }
    __syncthreads();
    for (int i = beg + tid; i < end; i += 256) {
        int p  = packed[i];
        int pos = beg + atomicAdd(&cnt[(p >> 17) & 63], 1);
        src_srt[pos] = p & SRC_MASK;
    }
}

// y = fp16(dis ⊙ emb), float4 in, half2 out
__global__ void prescale_kernel(const float4* __restrict__ emb4, const float* __restrict__ dis,
                                __half2* __restrict__ y2) {
    int i = blockIdx.x * blockDim.x + threadIdx.x;
    int stride = gridDim.x * blockDim.x;
    const int n4 = NUM_NODES * EMB_DIM / 4;
    for (; i < n4; i += stride) {
        float d = dis[i >> 4];               // 16 float4s per row
        float4 v = emb4[i];
        y2[2 * i]     = __floats2half2_rn(v.x * d, v.y * d);
        y2[2 * i + 1] = __floats2half2_rn(v.z * d, v.w * d);
    }
}

// ---------------------------------------------------------------------------
// Wave per node. half2 lanes: lane = (edge parity: lane>>5, dim pair: lane&31).
// 32-edge main loop -> 16 independent half2 gathers in flight per lane.
// beg/end readfirstlane'd -> index loads are scalar s_loads. Streaming traffic
// (yout/outw/emb) is nontemporal (via u32 bridge) so the 4 MB/XCD L2 stays
// reserved for yin row reuse.
//  mode 0: yout = h(dn*x); outw = h(alpha*(emb + x))
//  mode 1: yout = h(dn*x); outw += alpha*x
//  mode 2:                 outw += alpha*x
__global__ __launch_bounds__(256) void prop_kernel(
        const int* __restrict__ offs, const int* __restrict__ src_s,
        const float* __restrict__ dis, const __half2* __restrict__ yin2,
        __half2* __restrict__ yout2, const float2* __restrict__ emb2,
        __half2* __restrict__ outw2, float alpha, int mode) {
    int wid  = (blockIdx.x * blockDim.x + threadIdx.x) >> 6;
    int lane = threadIdx.x & 63;
    if (wid >= NUM_NODES) return;
    int sub = lane & 31;                 // dim pair
    int par = lane >> 5;                 // edge parity (0/1)
    int beg = __builtin_amdgcn_readfirstlane(offs[wid]);
    int end = __builtin_amdgcn_readfirstlane(offs[wid + 1]);
    float ax = 0.0f, ay = 0.0f;
    int j = beg;
    // 32 edges per iteration: 16 independent half2 gathers in flight per lane
    for (; j + 32 <= end; j += 32) {
        int s[16];
        #pragma unroll
        for (int t = 0; t < 16; ++t) {
            int e0 = src_s[j + 2 * t];
            int e1 = src_s[j + 2 * t + 1];
            s[t] = par ? e1 : e0;
        }
        __half2 h[16];
        #pragma unroll
        for (int t = 0; t < 16; ++t) h[t] = yin2[(s[t] << 5) + sub];
        #pragma unroll
        for (int t = 0; t < 16; ++t) {
            float2 f = __half22float2(h[t]);
            ax += f.x; ay += f.y;
        }
    }
    // 8-edge blocks
    for (; j + 8 <= end; j += 8) {
        int s[4];
        #pragma unroll
        for (int t = 0; t < 4; ++t) {
            int e0 = src_s[j + 2 * t];
            int e1 = src_s[j + 2 * t + 1];
            s[t] = par ? e1 : e0;
        }
        __half2 h[4];
        #pragma unroll
        for (int t = 0; t < 4; ++t) h[t] = yin2[(s[t] << 5) + sub];
        #pragma unroll
        for (int t = 0; t < 4; ++t) {
            float2 f = __half22float2(h[t]);
            ax += f.x; ay += f.y;
        }
    }
    // pair tail
    for (; j + 2 <= end; j += 2) {
        int s = src_s[j + par];
        float2 f = __half22float2(yin2[(s << 5) + sub]);
        ax += f.x; ay += f.y;
    }
    // odd single edge: parity-0 lanes only
    if (j < end && par == 0) {
        int s = src_s[j];
        float2 f = __half22float2(yin2[(s << 5) + sub]);
        ax += f.x; ay += f.y;
    }
    // merge the two parity streams
    ax += __shfl_xor(ax, 32);
    ay += __shfl_xor(ay, 32);

    float dn = dis[wid];
    float xx = dn * ax, xy = dn * ay;    // x_{l+1} dim pair
    int o2 = (wid << 5) + sub;
    unsigned* yout_u = (unsigned*)yout2;
    unsigned* outw_u = (unsigned*)outw2;
    const float* emb_f = (const float*)emb2;
    if (mode == 0) {
        if (par == 0) {
            __builtin_nontemporal_store(h2_as_u32(__floats2half2_rn(dn * xx, dn * xy)),
                                        &yout_u[o2]);
        } else {
            float ex = __builtin_nontemporal_load(&emb_f[2 * o2]);
            float ey = __builtin_nontemporal_load(&emb_f[2 * o2 + 1]);
            __builtin_nontemporal_store(
                h2_as_u32(__floats2half2_rn(alpha * (ex + xx), alpha * (ey + xy))),
                &outw_u[o2]);
        }
    } else if (mode == 1) {
        if (par == 0) {
            __builtin_nontemporal_store(h2_as_u32(__floats2half2_rn(dn * xx, dn * xy)),
                                        &yout_u[o2]);
        } else {
            float2 w = __half22float2(u32_as_h2(__builtin_nontemporal_load(&outw_u[o2])));
            __builtin_nontemporal_store(
                h2_as_u32(__floats2half2_rn(fmaf(alpha, xx, w.x), fmaf(alpha, xy, w.y))),
                &outw_u[o2]);
        }
    } else {
        if (par == 1) {
            float2 w = __half22float2(u32_as_h2(__builtin_nontemporal_load(&outw_u[o2])));
            __builtin_nontemporal_store(
                h2_as_u32(__floats2half2_rn(fmaf(alpha, xx, w.x), fmaf(alpha, xy, w.y))),
                &outw_u[o2]);
        }
    }
}

// ---------------------------------------------------------------------------
// packed fp16 dot-accumulate: v_dot2_f32_f16 where available, float2 fallback
#if defined(__has_builtin)
#if __has_builtin(__builtin_amdgcn_fdot2)
#define HAVE_FDOT2 1
#endif
#endif

#ifdef HAVE_FDOT2
typedef _Float16 hv2 __attribute__((ext_vector_type(2)));
__device__ __forceinline__ float dot2acc(unsigned a, unsigned b, float c) {
    hv2 ha, hb;
    __builtin_memcpy(&ha, &a, 4);
    __builtin_memcpy(&hb, &b, 4);
    return __builtin_amdgcn_fdot2(ha, hb, c, false);
}
#else
__device__ __forceinline__ float dot2acc(unsigned a, unsigned b, float c) {
    float2 fa = __half22float2(*(const __half2*)&a);
    float2 fb = __half22float2(*(const __half2*)&b);
    return fmaf(fa.y, fb.y, fmaf(fa.x, fb.x, c));
}
#endif

// 16 queries per wave, 4 lanes per query, fp16 rows (128 B), fp32 accumulate.
__global__ __launch_bounds__(256) void score_kernel(
        const int* __restrict__ qa, const int* __restrict__ qb,
        const uint4* __restrict__ x4, float* __restrict__ res) {
    int wave = (blockIdx.x * blockDim.x + threadIdx.x) >> 6;
    int lane = threadIdx.x & 63;
    int g = lane >> 2;                   // query slot in wave (0..15)
    int k = lane & 3;                    // chunk lane (0..3)
    int q = (wave << 4) + g;
    int a = qa[q];
    int b = qb[q];
    const uint4* pa = x4 + (a << 3);     // 8 uint4 (= 64 halves) per row
    const uint4* pb = x4 + (b << 3);
    uint4 ua0 = pa[k];     uint4 ub0 = pb[k];
    uint4 ua1 = pa[4 + k]; uint4 ub1 = pb[4 + k];
    float p = 0.0f;
    p = dot2acc(ua0.x, ub0.x, p);
    p = dot2acc(ua0.y, ub0.y, p);
    p = dot2acc(ua0.z, ub0.z, p);
    p = dot2acc(ua0.w, ub0.w, p);
    p = dot2acc(ua1.x, ub1.x, p);
    p = dot2acc(ua1.y, ub1.y, p);
    p = dot2acc(ua1.z, ub1.z, p);
    p = dot2acc(ua1.w, ub1.w, p);
    p += __shfl_xor(p, 1);
    p += __shfl_xor(p, 2);
    if (k == 0) res[q] = p;
}

extern "C" void kernel_launch(void* const* d_in, const int* in_sizes, int n_in,
                              void* d_out, int out_size, void* d_ws, size_t ws_size,
                              hipStream_t stream) {
    const float* emb  = (const float*)d_in[0];
    const int*   edge = (const int*)d_in[1];   // [2][NUM_EDGES]: src then dst
    const int*   qidx = (const int*)d_in[2];   // [2][NUM_QUERY]
    float*       out  = (float*)d_out;         // [NUM_QUERY]

    const int* e_src = edge;
    const int* e_dst = edge + NUM_EDGES;
    const int* q_a   = qidx;
    const int* q_b   = qidx + NUM_QUERY;

    const size_t HBYTES = (size_t)NUM_NODES * EMB_DIM * sizeof(__half); // 12.8 MB
    char* ws = (char*)d_ws;
    size_t off = 0;
    auto carve = [&](size_t bytes) { void* p = ws + off; off += (bytes + 255) & ~(size_t)255; return p; };
    int*    hist_g  = (int*)   carve((size_t)NCHUNK * NBUCKETS * 4);   // 1.6 MB
    int*    bcnt    = (int*)   carve((size_t)NBUCKETS * 4);
    int*    boffs   = (int*)   carve((size_t)(NBUCKETS + 1) * 4);
    int*    offs    = (int*)   carve((size_t)(NUM_NODES + 1) * 4);
    float*  dis     = (float*) carve((size_t)NUM_NODES * 4);
    int*    packed  = (int*)   carve((size_t)NUM_EDGES * 4);   // 12.8 MB
    int*    src_srt = (int*)   carve((size_t)NUM_EDGES * 4);   // 12.8 MB
    __half* yA      = (__half*)carve(HBYTES);
    __half* yB      = (__half*)carve(HBYTES);
    __half* outw    = (__half*)carve(HBYTES);

    const float alpha = 1.0f / (NUM_LAYERS + 1);   // 0.25

    // ---- build exact dst-sorted CSR: chunked counting sort, zero global atomics
    chist_kernel<<<NCHUNK, 256, 0, stream>>>(e_dst, hist_g);
    bscan_kernel<<<(NBUCKETS * 64 + 255) / 256, 256, 0, stream>>>(hist_g, bcnt);
    scan_kernel<<<1, 1024, 0, stream>>>(bcnt, boffs);
    cscatter_kernel<<<NCHUNK * 2, 256, 0, stream>>>(e_src, e_dst, boffs, hist_g, packed);
    lsort_kernel<<<NBUCKETS, 256, 0, stream>>>(boffs, packed, offs, src_srt, dis);
    prescale_kernel<<<2048, 256, 0, stream>>>((const float4*)emb, dis, (__half2*)yA);

    // ---- 3 propagation layers (fp16 storage, fp32 math), out-accumulation fused
    const int PROP_BLOCKS = (NUM_NODES * 64 + 255) / 256;
    prop_kernel<<<PROP_BLOCKS, 256, 0, stream>>>(offs, src_srt, dis,
        (const __half2*)yA, (__half2*)yB, (const float2*)emb, (__half2*)outw, alpha, 0);
    prop_kernel<<<PROP_BLOCKS, 256, 0, stream>>>(offs, src_srt, dis,
        (const __half2*)yB, (__half2*)yA, (const float2*)emb, (__half2*)outw, alpha, 1);
    prop_kernel<<<PROP_BLOCKS, 256, 0, stream>>>(offs, src_srt, dis,
        (const __half2*)yA, (__half2*)yB, (const float2*)emb, (__half2*)outw, alpha, 2);

    // ---- scoring: 64 queries per 256-thread block (16 per wave)
    score_kernel<<<NUM_QUERY / 64, 256, 0, stream>>>(q_a, q_b, (const uint4*)outw, out);
}

// Round 15
// 310.665 us; speedup vs baseline: 1.0025x; 1.0025x over previous
//
#include <hip/hip_runtime.h>
#include <hip/hip_fp16.h>

#define NUM_NODES 100000
#define EMB_DIM   64
#define NUM_LAYERS 3
#define NUM_EDGES 3200000
#define NUM_QUERY 1000000

#define BSHIFT   6
#define BNODES   64                                    // nodes per bucket
#define NBUCKETS ((NUM_NODES + BNODES - 1) / BNODES)   // 1563
#define HALF1    782                                   // bucket split point
#define SRC_MASK 131071                                // 17 bits (NUM_NODES < 2^17)
#define NCHUNK   256
#define CHUNK    (NUM_EDGES / NCHUNK)                  // 12500 edges per chunk
#define CHUNK4   (CHUNK / 4)                           // 3125 int4 per chunk

// __half2 <-> u32 bit bridges for nontemporal builtins
__device__ __forceinline__ __half2 u32_as_h2(unsigned u) {
    __half2 h;
    __builtin_memcpy(&h, &u, 4);
    return h;
}
__device__ __forceinline__ unsigned h2_as_u32(__half2 h) {
    unsigned u;
    __builtin_memcpy(&u, &h, 4);
    return u;
}

// ---------------------------------------------------------------------------
// Pass 1: per-chunk bucket histogram in LDS -> hist_g[chunk][bucket]
__global__ __launch_bounds__(256) void chist_kernel(const int* __restrict__ keys,
                                                    int* __restrict__ hist_g) {
    __shared__ int h[NBUCKETS];
    int b = blockIdx.x, tid = threadIdx.x;
    for (int k = tid; k < NBUCKETS; k += 256) h[k] = 0;
    __syncthreads();
    const int4* k4 = (const int4*)(keys + b * CHUNK);
    for (int i = tid; i < CHUNK4; i += 256) {
        int4 d = k4[i];
        atomicAdd(&h[d.x >> BSHIFT], 1);
        atomicAdd(&h[d.y >> BSHIFT], 1);
        atomicAdd(&h[d.z >> BSHIFT], 1);
        atomicAdd(&h[d.w >> BSHIFT], 1);
    }
    __syncthreads();
    for (int k = tid; k < NBUCKETS; k += 256)
        hist_g[b * NBUCKETS + k] = h[k];
}

// Per-bucket exclusive scan across the 256 chunks (one wave per bucket, 4/lane).
__global__ void bscan_kernel(int* __restrict__ hist_g, int* __restrict__ bcnt) {
    int gw   = (blockIdx.x * blockDim.x + threadIdx.x) >> 6;
    int lane = threadIdx.x & 63;
    if (gw >= NBUCKETS) return;
    int v0 = hist_g[(4 * lane + 0) * NBUCKETS + gw];
    int v1 = hist_g[(4 * lane + 1) * NBUCKETS + gw];
    int v2 = hist_g[(4 * lane + 2) * NBUCKETS + gw];
    int v3 = hist_g[(4 * lane + 3) * NBUCKETS + gw];
    int quad = v0 + v1 + v2 + v3, x = quad;
    #pragma unroll
    for (int d = 1; d < 64; d <<= 1) {
        int y = __shfl_up(x, d);
        if (lane >= d) x += y;
    }
    int ex = x - quad;                    // exclusive prefix over chunks
    hist_g[(4 * lane + 0) * NBUCKETS + gw] = ex;
    hist_g[(4 * lane + 1) * NBUCKETS + gw] = ex + v0;
    hist_g[(4 * lane + 2) * NBUCKETS + gw] = ex + v0 + v1;
    hist_g[(4 * lane + 3) * NBUCKETS + gw] = ex + v0 + v1 + v2;
    if (lane == 63) bcnt[gw] = x;         // bucket total
}

// single-block scan over NBUCKETS (2 tiles): boffs[b+1] = inclusive sum
__global__ void scan_kernel(const int* __restrict__ bcnt, int* __restrict__ boffs) {
    __shared__ int tile[1024];
    __shared__ int carry;
    int t = threadIdx.x;
    if (t == 0) { carry = 0; boffs[0] = 0; }
    __syncthreads();
    for (int base = 0; base < NBUCKETS; base += 1024) {
        int v = (base + t < NBUCKETS) ? bcnt[base + t] : 0;
        tile[t] = v;
        __syncthreads();
        for (int d = 1; d < 1024; d <<= 1) {
            int add = (t >= d) ? tile[t - d] : 0;
            __syncthreads();
            tile[t] += add;
            __syncthreads();
        }
        int inc = tile[t] + carry;
        if (base + t < NBUCKETS) boffs[base + t + 1] = inc;
        __syncthreads();
        if (t == 1023) carry = inc;
        __syncthreads();
    }
}

// Pass 2: scatter via LDS cursors. 2 blocks per chunk, split by bucket range —
// every (chunk,bucket) segment still has exactly one writer block.
__global__ __launch_bounds__(256) void cscatter_kernel(
        const int* __restrict__ src, const int* __restrict__ dst,
        const int* __restrict__ boffs, const int* __restrict__ hist_g,
        int* __restrict__ packed) {
    __shared__ int cur[NBUCKETS];
    int b = blockIdx.x >> 1, half = blockIdx.x & 1;
    int LO = half ? HALF1 : 0;
    int HI = half ? NBUCKETS : HALF1;
    int tid = threadIdx.x;
    for (int k = tid; k < NBUCKETS; k += 256)
        cur[k] = boffs[k] + hist_g[b * NBUCKETS + k];
    __syncthreads();
    const int4* s4 = (const int4*)(src + b * CHUNK);
    const int4* d4 = (const int4*)(dst + b * CHUNK);
    for (int i = tid; i < CHUNK4; i += 256) {
        int4 s = s4[i];
        int4 d = d4[i];
        int bk;
        bk = d.x >> BSHIFT;
        if (bk >= LO && bk < HI) { int p = atomicAdd(&cur[bk], 1); packed[p] = s.x | ((d.x & 63) << 17); }
        bk = d.y >> BSHIFT;
        if (bk >= LO && bk < HI) { int p = atomicAdd(&cur[bk], 1); packed[p] = s.y | ((d.y & 63) << 17); }
        bk = d.z >> BSHIFT;
        if (bk >= LO && bk < HI) { int p = atomicAdd(&cur[bk], 1); packed[p] = s.z | ((d.z & 63) << 17); }
        bk = d.w >> BSHIFT;
        if (bk >= LO && bk < HI) { int p = atomicAdd(&cur[bk], 1); packed[p] = s.w | ((d.w & 63) << 17); }
    }
}

// per-bucket local counting sort -> exact per-node CSR (src_srt, offs) + dis
__global__ __launch_bounds__(256) void lsort_kernel(
        const int* __restrict__ boffs, const int* __restrict__ packed,
        int* __restrict__ offs, int* __restrict__ src_srt, float* __restrict__ dis) {
    __shared__ int cnt[BNODES];
    int b   = blockIdx.x;
    int tid = threadIdx.x;
    int beg = boffs[b];
    int end = boffs[b + 1];
    if (tid < BNODES) cnt[tid] = 0;
    __syncthreads();
    for (int i = beg + tid; i < end; i += 256)
        atomicAdd(&cnt[(packed[i] >> 17) & 63], 1);
    __syncthreads();
    if (tid < 64) {                      // wave 0: exclusive scan of 64 counters
        int v = cnt[tid];
        int x = v;
        #pragma unroll
        for (int d = 1; d < 64; d <<= 1) {
            int y = __shfl_up(x, d);
            if (tid >= d) x += y;
        }
        int ex = x - v;                  // exclusive prefix
        int node = (b << BSHIFT) + tid;
        if (node <= NUM_NODES) offs[node] = beg + ex;   // bucket 1562/tid 32 writes offs[N]=E
        if (node <  NUM_NODES) dis[node] = (v > 0) ? rsqrtf((float)v) : 0.0f;
        cnt[tid] = ex;                   // reuse as local cursor
    }
    __syncthreads();
    for (int i = beg + tid; i < end; i += 256) {
        int p  = packed[i];
        int pos = beg + atomicAdd(&cnt[(p >> 17) & 63], 1);
        src_srt[pos] = p & SRC_MASK;
    }
}

// y = fp16(dis ⊙ emb), float4 in, half2 out
__global__ void prescale_kernel(const float4* __restrict__ emb4, const float* __restrict__ dis,
                                __half2* __restrict__ y2) {
    int i = blockIdx.x * blockDim.x + threadIdx.x;
    int stride = gridDim.x * blockDim.x;
    const int n4 = NUM_NODES * EMB_DIM / 4;
    for (; i < n4; i += stride) {
        float d = dis[i >> 4];               // 16 float4s per row
        float4 v = emb4[i];
        y2[2 * i]     = __floats2half2_rn(v.x * d, v.y * d);
        y2[2 * i + 1] = __floats2half2_rn(v.z * d, v.w * d);
    }
}

// ---------------------------------------------------------------------------
// Wave per node. half2 lanes: lane = (edge parity: lane>>5, dim pair: lane&31).
// 16-edge main loop (R12 structure — best measured) -> 8 independent half2
// gathers in flight per lane; beg/end readfirstlane'd -> index loads scalar.
// NT epilogue (yout/outw/emb via u32 bridge) keeps the 4 MB/XCD L2 reserved
// for yin row reuse.
//  mode 0: yout = h(dn*x); outw = h(alpha*(emb + x))
//  mode 1: yout = h(dn*x); outw += alpha*x
//  mode 2:                 outw += alpha*x
__global__ __launch_bounds__(256) void prop_kernel(
        const int* __restrict__ offs, const int* __restrict__ src_s,
        const float* __restrict__ dis, const __half2* __restrict__ yin2,
        __half2* __restrict__ yout2, const float2* __restrict__ emb2,
        __half2* __restrict__ outw2, float alpha, int mode) {
    int wid  = (blockIdx.x * blockDim.x + threadIdx.x) >> 6;
    int lane = threadIdx.x & 63;
    if (wid >= NUM_NODES) return;
    int sub = lane & 31;                 // dim pair
    int par = lane >> 5;                 // edge parity (0/1)
    int beg = __builtin_amdgcn_readfirstlane(offs[wid]);
    int end = __builtin_amdgcn_readfirstlane(offs[wid + 1]);
    float ax = 0.0f, ay = 0.0f;
    int j = beg;
    // 16 edges per iteration: 8 independent half2 gathers in flight per lane
    for (; j + 16 <= end; j += 16) {
        int i0  = src_s[j + 0],  i1  = src_s[j + 1];
        int i2  = src_s[j + 2],  i3  = src_s[j + 3];
        int i4  = src_s[j + 4],  i5  = src_s[j + 5];
        int i6  = src_s[j + 6],  i7  = src_s[j + 7];
        int i8  = src_s[j + 8],  i9  = src_s[j + 9];
        int i10 = src_s[j + 10], i11 = src_s[j + 11];
        int i12 = src_s[j + 12], i13 = src_s[j + 13];
        int i14 = src_s[j + 14], i15 = src_s[j + 15];
        int s0 = par ? i1  : i0;
        int s1 = par ? i3  : i2;
        int s2 = par ? i5  : i4;
        int s3 = par ? i7  : i6;
        int s4 = par ? i9  : i8;
        int s5 = par ? i11 : i10;
        int s6 = par ? i13 : i12;
        int s7 = par ? i15 : i14;
        __half2 h0 = yin2[(s0 << 5) + sub];
        __half2 h1 = yin2[(s1 << 5) + sub];
        __half2 h2 = yin2[(s2 << 5) + sub];
        __half2 h3 = yin2[(s3 << 5) + sub];
        __half2 h4 = yin2[(s4 << 5) + sub];
        __half2 h5 = yin2[(s5 << 5) + sub];
        __half2 h6 = yin2[(s6 << 5) + sub];
        __half2 h7 = yin2[(s7 << 5) + sub];
        float2 f0 = __half22float2(h0);
        float2 f1 = __half22float2(h1);
        float2 f2 = __half22float2(h2);
        float2 f3 = __half22float2(h3);
        float2 f4 = __half22float2(h4);
        float2 f5 = __half22float2(h5);
        float2 f6 = __half22float2(h6);
        float2 f7 = __half22float2(h7);
        ax += ((f0.x + f1.x) + (f2.x + f3.x)) + ((f4.x + f5.x) + (f6.x + f7.x));
        ay += ((f0.y + f1.y) + (f2.y + f3.y)) + ((f4.y + f5.y) + (f6.y + f7.y));
    }
    // 8-edge block
    if (j + 8 <= end) {
        int i0 = src_s[j + 0], i1 = src_s[j + 1];
        int i2 = src_s[j + 2], i3 = src_s[j + 3];
        int i4 = src_s[j + 4], i5 = src_s[j + 5];
        int i6 = src_s[j + 6], i7 = src_s[j + 7];
        int s0 = par ? i1 : i0;
        int s1 = par ? i3 : i2;
        int s2 = par ? i5 : i4;
        int s3 = par ? i7 : i6;
        __half2 h0 = yin2[(s0 << 5) + sub];
        __half2 h1 = yin2[(s1 << 5) + sub];
        __half2 h2 = yin2[(s2 << 5) + sub];
        __half2 h3 = yin2[(s3 << 5) + sub];
        float2 f0 = __half22float2(h0);
        float2 f1 = __half22float2(h1);
        float2 f2 = __half22float2(h2);
        float2 f3 = __half22float2(h3);
        ax += (f0.x + f1.x) + (f2.x + f3.x);
        ay += (f0.y + f1.y) + (f2.y + f3.y);
        j += 8;
    }
    // pair tail
    for (; j + 2 <= end; j += 2) {
        int s = src_s[j + par];
        float2 f = __half22float2(yin2[(s << 5) + sub]);
        ax += f.x; ay += f.y;
    }
    // odd single edge: parity-0 lanes only
    if (j < end && par == 0) {
        int s = src_s[j];
        float2 f = __half22float2(yin2[(s << 5) + sub]);
        ax += f.x; ay += f.y;
    }
    // merge the two parity streams
    ax += __shfl_xor(ax, 32);
    ay += __shfl_xor(ay, 32);

    float dn = dis[wid];
    float xx = dn * ax, xy = dn * ay;    // x_{l+1} dim pair
    int o2 = (wid << 5) + sub;
    unsigned* yout_u = (unsigned*)yout2;
    unsigned* outw_u = (unsigned*)outw2;
    const float* emb_f = (const float*)emb2;
    if (mode == 0) {
        if (par == 0) {
            __builtin_nontemporal_store(h2_as_u32(__floats2half2_rn(dn * xx, dn * xy)),
                                        &yout_u[o2]);
        } else {
            float ex = __builtin_nontemporal_load(&emb_f[2 * o2]);
            float ey = __builtin_nontemporal_load(&emb_f[2 * o2 + 1]);
            __builtin_nontemporal_store(
                h2_as_u32(__floats2half2_rn(alpha * (ex + xx), alpha * (ey + xy))),
                &outw_u[o2]);
        }
    } else if (mode == 1) {
        if (par == 0) {
            __builtin_nontemporal_store(h2_as_u32(__floats2half2_rn(dn * xx, dn * xy)),
                                        &yout_u[o2]);
        } else {
            float2 w = __half22float2(u32_as_h2(__builtin_nontemporal_load(&outw_u[o2])));
            __builtin_nontemporal_store(
                h2_as_u32(__floats2half2_rn(fmaf(alpha, xx, w.x), fmaf(alpha, xy, w.y))),
                &outw_u[o2]);
        }
    } else {
        if (par == 1) {
            float2 w = __half22float2(u32_as_h2(__builtin_nontemporal_load(&outw_u[o2])));
            __builtin_nontemporal_store(
                h2_as_u32(__floats2half2_rn(fmaf(alpha, xx, w.x), fmaf(alpha, xy, w.y))),
                &outw_u[o2]);
        }
    }
}

// ---------------------------------------------------------------------------
// packed fp16 dot-accumulate: v_dot2_f32_f16 where available, float2 fallback
#if defined(__has_builtin)
#if __has_builtin(__builtin_amdgcn_fdot2)
#define HAVE_FDOT2 1
#endif
#endif

#ifdef HAVE_FDOT2
typedef _Float16 hv2 __attribute__((ext_vector_type(2)));
__device__ __forceinline__ float dot2acc(unsigned a, unsigned b, float c) {
    hv2 ha, hb;
    __builtin_memcpy(&ha, &a, 4);
    __builtin_memcpy(&hb, &b, 4);
    return __builtin_amdgcn_fdot2(ha, hb, c, false);
}
#else
__device__ __forceinline__ float dot2acc(unsigned a, unsigned b, float c) {
    float2 fa = __half22float2(*(const __half2*)&a);
    float2 fb = __half22float2(*(const __half2*)&b);
    return fmaf(fa.y, fb.y, fmaf(fa.x, fb.x, c));
}
#endif

// 16 queries per wave, 4 lanes per query, fp16 rows (128 B), fp32 accumulate.
__global__ __launch_bounds__(256) void score_kernel(
        const int* __restrict__ qa, const int* __restrict__ qb,
        const uint4* __restrict__ x4, float* __restrict__ res) {
    int wave = (blockIdx.x * blockDim.x + threadIdx.x) >> 6;
    int lane = threadIdx.x & 63;
    int g = lane >> 2;                   // query slot in wave (0..15)
    int k = lane & 3;                    // chunk lane (0..3)
    int q = (wave << 4) + g;
    int a = qa[q];
    int b = qb[q];
    const uint4* pa = x4 + (a << 3);     // 8 uint4 (= 64 halves) per row
    const uint4* pb = x4 + (b << 3);
    uint4 ua0 = pa[k];     uint4 ub0 = pb[k];
    uint4 ua1 = pa[4 + k]; uint4 ub1 = pb[4 + k];
    float p = 0.0f;
    p = dot2acc(ua0.x, ub0.x, p);
    p = dot2acc(ua0.y, ub0.y, p);
    p = dot2acc(ua0.z, ub0.z, p);
    p = dot2acc(ua0.w, ub0.w, p);
    p = dot2acc(ua1.x, ub1.x, p);
    p = dot2acc(ua1.y, ub1.y, p);
    p = dot2acc(ua1.z, ub1.z, p);
    p = dot2acc(ua1.w, ub1.w, p);
    p += __shfl_xor(p, 1);
    p += __shfl_xor(p, 2);
    if (k == 0) res[q] = p;
}

extern "C" void kernel_launch(void* const* d_in, const int* in_sizes, int n_in,
                              void* d_out, int out_size, void* d_ws, size_t ws_size,
                              hipStream_t stream) {
    const float* emb  = (const float*)d_in[0];
    const int*   edge = (const int*)d_in[1];   // [2][NUM_EDGES]: src then dst
    const int*   qidx = (const int*)d_in[2];   // [2][NUM_QUERY]
    float*       out  = (float*)d_out;         // [NUM_QUERY]

    const int* e_src = edge;
    const int* e_dst = edge + NUM_EDGES;
    const int* q_a   = qidx;
    const int* q_b   = qidx + NUM_QUERY;

    const size_t HBYTES = (size_t)NUM_NODES * EMB_DIM * sizeof(__half); // 12.8 MB
    char* ws = (char*)d_ws;
    size_t off = 0;
    auto carve = [&](size_t bytes) { void* p = ws + off; off += (bytes + 255) & ~(size_t)255; return p; };
    int*    hist_g  = (int*)   carve((size_t)NCHUNK * NBUCKETS * 4);   // 1.6 MB
    int*    bcnt    = (int*)   carve((size_t)NBUCKETS * 4);
    int*    boffs   = (int*)   carve((size_t)(NBUCKETS + 1) * 4);
    int*    offs    = (int*)   carve((size_t)(NUM_NODES + 1) * 4);
    float*  dis     = (float*) carve((size_t)NUM_NODES * 4);
    int*    packed  = (int*)   carve((size_t)NUM_EDGES * 4);   // 12.8 MB
    int*    src_srt = (int*)   carve((size_t)NUM_EDGES * 4);   // 12.8 MB
    __half* yA      = (__half*)carve(HBYTES);
    __half* yB      = (__half*)carve(HBYTES);
    __half* outw    = (__half*)carve(HBYTES);

    const float alpha = 1.0f / (NUM_LAYERS + 1);   // 0.25

    // ---- build exact dst-sorted CSR: chunked counting sort, zero global atomics
    chist_kernel<<<NCHUNK, 256, 0, stream>>>(e_dst, hist_g);
    bscan_kernel<<<(NBUCKETS * 64 + 255) / 256, 256, 0, stream>>>(hist_g, bcnt);
    scan_kernel<<<1, 1024, 0, stream>>>(bcnt, boffs);
    cscatter_kernel<<<NCHUNK * 2, 256, 0, stream>>>(e_src, e_dst, boffs, hist_g, packed);
    lsort_kernel<<<NBUCKETS, 256, 0, stream>>>(boffs, packed, offs, src_srt, dis);
    prescale_kernel<<<2048, 256, 0, stream>>>((const float4*)emb, dis, (__half2*)yA);

    // ---- 3 propagation layers (fp16 storage, fp32 math), out-accumulation fused
    const int PROP_BLOCKS = (NUM_NODES * 64 + 255) / 256;
    prop_kernel<<<PROP_BLOCKS, 256, 0, stream>>>(offs, src_srt, dis,
        (const __half2*)yA, (__half2*)yB, (const float2*)emb, (__half2*)outw, alpha, 0);
    prop_kernel<<<PROP_BLOCKS, 256, 0, stream>>>(offs, src_srt, dis,
        (const __half2*)yB, (__half2*)yA, (const float2*)emb, (__half2*)outw, alpha, 1);
    prop_kernel<<<PROP_BLOCKS, 256, 0, stream>>>(offs, src_srt, dis,
        (const __half2*)yA, (__half2*)yB, (const float2*)emb, (__half2*)outw, alpha, 2);

    // ---- scoring: 64 queries per 256-thread block (16 per wave)
    score_kernel<<<NUM_QUERY / 64, 256, 0, stream>>>(q_a, q_b, (const uint4*)outw, out);
}

// Round 16
// 299.736 us; speedup vs baseline: 1.0390x; 1.0365x over previous
//
#include <hip/hip_runtime.h>
#include <hip/hip_fp16.h>

#define NUM_NODES 100000
#define EMB_DIM   64
#define NUM_LAYERS 3
#define NUM_EDGES 3200000
#define NUM_QUERY 1000000

#define BSHIFT   6
#define BNODES   64                                    // nodes per bucket
#define NBUCKETS ((NUM_NODES + BNODES - 1) / BNODES)   // 1563
#define HALF1    782                                   // bucket split point
#define SRC_MASK 131071                                // 17 bits (NUM_NODES < 2^17)
#define NCHUNK   256
#define CHUNK    (NUM_EDGES / NCHUNK)                  // 12500 edges per chunk
#define CHUNK4   (CHUNK / 4)                           // 3125 int4 per chunk

// ---------------------------------------------------------------------------
// Pass 1: per-chunk bucket histogram in LDS -> hist_g[chunk][bucket]
__global__ __launch_bounds__(256) void chist_kernel(const int* __restrict__ keys,
                                                    int* __restrict__ hist_g) {
    __shared__ int h[NBUCKETS];
    int b = blockIdx.x, tid = threadIdx.x;
    for (int k = tid; k < NBUCKETS; k += 256) h[k] = 0;
    __syncthreads();
    const int4* k4 = (const int4*)(keys + b * CHUNK);
    for (int i = tid; i < CHUNK4; i += 256) {
        int4 d = k4[i];
        atomicAdd(&h[d.x >> BSHIFT], 1);
        atomicAdd(&h[d.y >> BSHIFT], 1);
        atomicAdd(&h[d.z >> BSHIFT], 1);
        atomicAdd(&h[d.w >> BSHIFT], 1);
    }
    __syncthreads();
    for (int k = tid; k < NBUCKETS; k += 256)
        hist_g[b * NBUCKETS + k] = h[k];
}

// Per-bucket exclusive scan across the 256 chunks (one wave per bucket, 4/lane).
__global__ void bscan_kernel(int* __restrict__ hist_g, int* __restrict__ bcnt) {
    int gw   = (blockIdx.x * blockDim.x + threadIdx.x) >> 6;
    int lane = threadIdx.x & 63;
    if (gw >= NBUCKETS) return;
    int v0 = hist_g[(4 * lane + 0) * NBUCKETS + gw];
    int v1 = hist_g[(4 * lane + 1) * NBUCKETS + gw];
    int v2 = hist_g[(4 * lane + 2) * NBUCKETS + gw];
    int v3 = hist_g[(4 * lane + 3) * NBUCKETS + gw];
    int quad = v0 + v1 + v2 + v3, x = quad;
    #pragma unroll
    for (int d = 1; d < 64; d <<= 1) {
        int y = __shfl_up(x, d);
        if (lane >= d) x += y;
    }
    int ex = x - quad;                    // exclusive prefix over chunks
    hist_g[(4 * lane + 0) * NBUCKETS + gw] = ex;
    hist_g[(4 * lane + 1) * NBUCKETS + gw] = ex + v0;
    hist_g[(4 * lane + 2) * NBUCKETS + gw] = ex + v0 + v1;
    hist_g[(4 * lane + 3) * NBUCKETS + gw] = ex + v0 + v1 + v2;
    if (lane == 63) bcnt[gw] = x;         // bucket total
}

// single-block scan over NBUCKETS (2 tiles): boffs[b+1] = inclusive sum
__global__ void scan_kernel(const int* __restrict__ bcnt, int* __restrict__ boffs) {
    __shared__ int tile[1024];
    __shared__ int carry;
    int t = threadIdx.x;
    if (t == 0) { carry = 0; boffs[0] = 0; }
    __syncthreads();
    for (int base = 0; base < NBUCKETS; base += 1024) {
        int v = (base + t < NBUCKETS) ? bcnt[base + t] : 0;
        tile[t] = v;
        __syncthreads();
        for (int d = 1; d < 1024; d <<= 1) {
            int add = (t >= d) ? tile[t - d] : 0;
            __syncthreads();
            tile[t] += add;
            __syncthreads();
        }
        int inc = tile[t] + carry;
        if (base + t < NBUCKETS) boffs[base + t + 1] = inc;
        __syncthreads();
        if (t == 1023) carry = inc;
        __syncthreads();
    }
}

// Pass 2: scatter via LDS cursors. 2 blocks per chunk, split by bucket range —
// every (chunk,bucket) segment still has exactly one writer block.
__global__ __launch_bounds__(256) void cscatter_kernel(
        const int* __restrict__ src, const int* __restrict__ dst,
        const int* __restrict__ boffs, const int* __restrict__ hist_g,
        int* __restrict__ packed) {
    __shared__ int cur[NBUCKETS];
    int b = blockIdx.x >> 1, half = blockIdx.x & 1;
    int LO = half ? HALF1 : 0;
    int HI = half ? NBUCKETS : HALF1;
    int tid = threadIdx.x;
    for (int k = tid; k < NBUCKETS; k += 256)
        cur[k] = boffs[k] + hist_g[b * NBUCKETS + k];
    __syncthreads();
    const int4* s4 = (const int4*)(src + b * CHUNK);
    const int4* d4 = (const int4*)(dst + b * CHUNK);
    for (int i = tid; i < CHUNK4; i += 256) {
        int4 s = s4[i];
        int4 d = d4[i];
        int bk;
        bk = d.x >> BSHIFT;
        if (bk >= LO && bk < HI) { int p = atomicAdd(&cur[bk], 1); packed[p] = s.x | ((d.x & 63) << 17); }
        bk = d.y >> BSHIFT;
        if (bk >= LO && bk < HI) { int p = atomicAdd(&cur[bk], 1); packed[p] = s.y | ((d.y & 63) << 17); }
        bk = d.z >> BSHIFT;
        if (bk >= LO && bk < HI) { int p = atomicAdd(&cur[bk], 1); packed[p] = s.z | ((d.z & 63) << 17); }
        bk = d.w >> BSHIFT;
        if (bk >= LO && bk < HI) { int p = atomicAdd(&cur[bk], 1); packed[p] = s.w | ((d.w & 63) << 17); }
    }
}

// per-bucket local counting sort -> exact per-node CSR (src_srt, offs) + dis
__global__ __launch_bounds__(256) void lsort_kernel(
        const int* __restrict__ boffs, const int* __restrict__ packed,
        int* __restrict__ offs, int* __restrict__ src_srt, float* __restrict__ dis) {
    __shared__ int cnt[BNODES];
    int b   = blockIdx.x;
    int tid = threadIdx.x;
    int beg = boffs[b];
    int end = boffs[b + 1];
    if (tid < BNODES) cnt[tid] = 0;
    __syncthreads();
    for (int i = beg + tid; i < end; i += 256)
        atomicAdd(&cnt[(packed[i] >> 17) & 63], 1);
    __syncthreads();
    if (tid < 64) {                      // wave 0: exclusive scan of 64 counters
        int v = cnt[tid];
        int x = v;
        #pragma unroll
        for (int d = 1; d < 64; d <<= 1) {
            int y = __shfl_up(x, d);
            if (tid >= d) x += y;
        }
        int ex = x - v;                  // exclusive prefix
        int node = (b << BSHIFT) + tid;
        if (node <= NUM_NODES) offs[node] = beg + ex;   // bucket 1562/tid 32 writes offs[N]=E
        if (node <  NUM_NODES) dis[node] = (v > 0) ? rsqrtf((float)v) : 0.0f;
        cnt[tid] = ex;                   // reuse as local cursor
    }
    __syncthreads();
    for (int i = beg + tid; i < end; i += 256) {
        int p  = packed[i];
        int pos = beg + atomicAdd(&cnt[(p >> 17) & 63], 1);
        src_srt[pos] = p & SRC_MASK;
    }
}

// y = fp16(dis ⊙ emb), float4 in, half2 out
__global__ void prescale_kernel(const float4* __restrict__ emb4, const float* __restrict__ dis,
                                __half2* __restrict__ y2) {
    int i = blockIdx.x * blockDim.x + threadIdx.x;
    int stride = gridDim.x * blockDim.x;
    const int n4 = NUM_NODES * EMB_DIM / 4;
    for (; i < n4; i += stride) {
        float d = dis[i >> 4];               // 16 float4s per row
        float4 v = emb4[i];
        y2[2 * i]     = __floats2half2_rn(v.x * d, v.y * d);
        y2[2 * i + 1] = __floats2half2_rn(v.z * d, v.w * d);
    }
}

// ---------------------------------------------------------------------------
// Wave per node. half2 lanes: lane = (edge parity: lane>>5, dim pair: lane&31).
// 16-edge main loop -> 8 independent half2 gathers in flight per wave; beg/end
// readfirstlane'd so index loads are scalar s_loads (off the VMEM queue).
// No nontemporal: yout/outw are the NEXT layer's inputs — keep them cached.
//  mode 0: yout = h(dn*x); outw = h(alpha*(emb + x))
//  mode 1: yout = h(dn*x); outw += alpha*x
//  mode 2:                 outw += alpha*x
__global__ __launch_bounds__(256) void prop_kernel(
        const int* __restrict__ offs, const int* __restrict__ src_s,
        const float* __restrict__ dis, const __half2* __restrict__ yin2,
        __half2* __restrict__ yout2, const float2* __restrict__ emb2,
        __half2* __restrict__ outw2, float alpha, int mode) {
    int wid  = (blockIdx.x * blockDim.x + threadIdx.x) >> 6;
    int lane = threadIdx.x & 63;
    if (wid >= NUM_NODES) return;
    int sub = lane & 31;                 // dim pair
    int par = lane >> 5;                 // edge parity (0/1)
    int beg = __builtin_amdgcn_readfirstlane(offs[wid]);
    int end = __builtin_amdgcn_readfirstlane(offs[wid + 1]);
    float ax = 0.0f, ay = 0.0f;
    int j = beg;
    // 16 edges per iteration: 8 independent half2 gathers in flight per lane
    for (; j + 16 <= end; j += 16) {
        int i0  = src_s[j + 0],  i1  = src_s[j + 1];
        int i2  = src_s[j + 2],  i3  = src_s[j + 3];
        int i4  = src_s[j + 4],  i5  = src_s[j + 5];
        int i6  = src_s[j + 6],  i7  = src_s[j + 7];
        int i8  = src_s[j + 8],  i9  = src_s[j + 9];
        int i10 = src_s[j + 10], i11 = src_s[j + 11];
        int i12 = src_s[j + 12], i13 = src_s[j + 13];
        int i14 = src_s[j + 14], i15 = src_s[j + 15];
        int s0 = par ? i1  : i0;
        int s1 = par ? i3  : i2;
        int s2 = par ? i5  : i4;
        int s3 = par ? i7  : i6;
        int s4 = par ? i9  : i8;
        int s5 = par ? i11 : i10;
        int s6 = par ? i13 : i12;
        int s7 = par ? i15 : i14;
        __half2 h0 = yin2[(s0 << 5) + sub];
        __half2 h1 = yin2[(s1 << 5) + sub];
        __half2 h2 = yin2[(s2 << 5) + sub];
        __half2 h3 = yin2[(s3 << 5) + sub];
        __half2 h4 = yin2[(s4 << 5) + sub];
        __half2 h5 = yin2[(s5 << 5) + sub];
        __half2 h6 = yin2[(s6 << 5) + sub];
        __half2 h7 = yin2[(s7 << 5) + sub];
        float2 f0 = __half22float2(h0);
        float2 f1 = __half22float2(h1);
        float2 f2 = __half22float2(h2);
        float2 f3 = __half22float2(h3);
        float2 f4 = __half22float2(h4);
        float2 f5 = __half22float2(h5);
        float2 f6 = __half22float2(h6);
        float2 f7 = __half22float2(h7);
        ax += ((f0.x + f1.x) + (f2.x + f3.x)) + ((f4.x + f5.x) + (f6.x + f7.x));
        ay += ((f0.y + f1.y) + (f2.y + f3.y)) + ((f4.y + f5.y) + (f6.y + f7.y));
    }
    // 8-edge block
    if (j + 8 <= end) {
        int i0 = src_s[j + 0], i1 = src_s[j + 1];
        int i2 = src_s[j + 2], i3 = src_s[j + 3];
        int i4 = src_s[j + 4], i5 = src_s[j + 5];
        int i6 = src_s[j + 6], i7 = src_s[j + 7];
        int s0 = par ? i1 : i0;
        int s1 = par ? i3 : i2;
        int s2 = par ? i5 : i4;
        int s3 = par ? i7 : i6;
        __half2 h0 = yin2[(s0 << 5) + sub];
        __half2 h1 = yin2[(s1 << 5) + sub];
        __half2 h2 = yin2[(s2 << 5) + sub];
        __half2 h3 = yin2[(s3 << 5) + sub];
        float2 f0 = __half22float2(h0);
        float2 f1 = __half22float2(h1);
        float2 f2 = __half22float2(h2);
        float2 f3 = __half22float2(h3);
        ax += (f0.x + f1.x) + (f2.x + f3.x);
        ay += (f0.y + f1.y) + (f2.y + f3.y);
        j += 8;
    }
    // pair tail
    for (; j + 2 <= end; j += 2) {
        int s = src_s[j + par];
        float2 f = __half22float2(yin2[(s << 5) + sub]);
        ax += f.x; ay += f.y;
    }
    // odd single edge: parity-0 lanes only
    if (j < end && par == 0) {
        int s = src_s[j];
        float2 f = __half22float2(yin2[(s << 5) + sub]);
        ax += f.x; ay += f.y;
    }
    // merge the two parity streams
    ax += __shfl_xor(ax, 32);
    ay += __shfl_xor(ay, 32);

    float dn = dis[wid];
    float xx = dn * ax, xy = dn * ay;    // x_{l+1} dim pair
    int o2 = (wid << 5) + sub;
    if (mode == 0) {
        if (par == 0) {
            yout2[o2] = __floats2half2_rn(dn * xx, dn * xy);
        } else {
            float2 e = emb2[o2];
            outw2[o2] = __floats2half2_rn(alpha * (e.x + xx), alpha * (e.y + xy));
        }
    } else if (mode == 1) {
        if (par == 0) {
            yout2[o2] = __floats2half2_rn(dn * xx, dn * xy);
        } else {
            float2 w = __half22float2(outw2[o2]);
            outw2[o2] = __floats2half2_rn(fmaf(alpha, xx, w.x), fmaf(alpha, xy, w.y));
        }
    } else {
        if (par == 1) {
            float2 w = __half22float2(outw2[o2]);
            outw2[o2] = __floats2half2_rn(fmaf(alpha, xx, w.x), fmaf(alpha, xy, w.y));
        }
    }
}

// ---------------------------------------------------------------------------
// packed fp16 dot-accumulate: v_dot2_f32_f16 where available, float2 fallback
#if defined(__has_builtin)
#if __has_builtin(__builtin_amdgcn_fdot2)
#define HAVE_FDOT2 1
#endif
#endif

#ifdef HAVE_FDOT2
typedef _Float16 hv2 __attribute__((ext_vector_type(2)));
__device__ __forceinline__ float dot2acc(unsigned a, unsigned b, float c) {
    hv2 ha, hb;
    __builtin_memcpy(&ha, &a, 4);
    __builtin_memcpy(&hb, &b, 4);
    return __builtin_amdgcn_fdot2(ha, hb, c, false);
}
#else
__device__ __forceinline__ float dot2acc(unsigned a, unsigned b, float c) {
    float2 fa = __half22float2(*(const __half2*)&a);
    float2 fb = __half22float2(*(const __half2*)&b);
    return fmaf(fa.y, fb.y, fmaf(fa.x, fb.x, c));
}
#endif

// 16 queries per wave, 4 lanes per query, fp16 rows (128 B), fp32 accumulate.
__global__ __launch_bounds__(256) void score_kernel(
        const int* __restrict__ qa, const int* __restrict__ qb,
        const uint4* __restrict__ x4, float* __restrict__ res) {
    int wave = (blockIdx.x * blockDim.x + threadIdx.x) >> 6;
    int lane = threadIdx.x & 63;
    int g = lane >> 2;                   // query slot in wave (0..15)
    int k = lane & 3;                    // chunk lane (0..3)
    int q = (wave << 4) + g;
    int a = qa[q];
    int b = qb[q];
    const uint4* pa = x4 + (a << 3);     // 8 uint4 (= 64 halves) per row
    const uint4* pb = x4 + (b << 3);
    uint4 ua0 = pa[k];     uint4 ub0 = pb[k];
    uint4 ua1 = pa[4 + k]; uint4 ub1 = pb[4 + k];
    float p = 0.0f;
    p = dot2acc(ua0.x, ub0.x, p);
    p = dot2acc(ua0.y, ub0.y, p);
    p = dot2acc(ua0.z, ub0.z, p);
    p = dot2acc(ua0.w, ub0.w, p);
    p = dot2acc(ua1.x, ub1.x, p);
    p = dot2acc(ua1.y, ub1.y, p);
    p = dot2acc(ua1.z, ub1.z, p);
    p = dot2acc(ua1.w, ub1.w, p);
    p += __shfl_xor(p, 1);
    p += __shfl_xor(p, 2);
    if (k == 0) res[q] = p;
}

extern "C" void kernel_launch(void* const* d_in, const int* in_sizes, int n_in,
                              void* d_out, int out_size, void* d_ws, size_t ws_size,
                              hipStream_t stream) {
    const float* emb  = (const float*)d_in[0];
    const int*   edge = (const int*)d_in[1];   // [2][NUM_EDGES]: src then dst
    const int*   qidx = (const int*)d_in[2];   // [2][NUM_QUERY]
    float*       out  = (float*)d_out;         // [NUM_QUERY]

    const int* e_src = edge;
    const int* e_dst = edge + NUM_EDGES;
    const int* q_a   = qidx;
    const int* q_b   = qidx + NUM_QUERY;

    const size_t HBYTES = (size_t)NUM_NODES * EMB_DIM * sizeof(__half); // 12.8 MB
    char* ws = (char*)d_ws;
    size_t off = 0;
    auto carve = [&](size_t bytes) { void* p = ws + off; off += (bytes + 255) & ~(size_t)255; return p; };
    int*    hist_g  = (int*)   carve((size_t)NCHUNK * NBUCKETS * 4);   // 1.6 MB
    int*    bcnt    = (int*)   carve((size_t)NBUCKETS * 4);
    int*    boffs   = (int*)   carve((size_t)(NBUCKETS + 1) * 4);
    int*    offs    = (int*)   carve((size_t)(NUM_NODES + 1) * 4);
    float*  dis     = (float*) carve((size_t)NUM_NODES * 4);
    int*    packed  = (int*)   carve((size_t)NUM_EDGES * 4);   // 12.8 MB
    int*    src_srt = (int*)   carve((size_t)NUM_EDGES * 4);   // 12.8 MB
    __half* yA      = (__half*)carve(HBYTES);
    __half* yB      = (__half*)carve(HBYTES);
    __half* outw    = (__half*)carve(HBYTES);

    const float alpha = 1.0f / (NUM_LAYERS + 1);   // 0.25

    // ---- build exact dst-sorted CSR: chunked counting sort, zero global atomics
    chist_kernel<<<NCHUNK, 256, 0, stream>>>(e_dst, hist_g);
    bscan_kernel<<<(NBUCKETS * 64 + 255) / 256, 256, 0, stream>>>(hist_g, bcnt);
    scan_kernel<<<1, 1024, 0, stream>>>(bcnt, boffs);
    cscatter_kernel<<<NCHUNK * 2, 256, 0, stream>>>(e_src, e_dst, boffs, hist_g, packed);
    lsort_kernel<<<NBUCKETS, 256, 0, stream>>>(boffs, packed, offs, src_srt, dis);
    prescale_kernel<<<2048, 256, 0, stream>>>((const float4*)emb, dis, (__half2*)yA);

    // ---- 3 propagation layers (fp16 storage, fp32 math), out-accumulation fused
    const int PROP_BLOCKS = (NUM_NODES * 64 + 255) / 256;
    prop_kernel<<<PROP_BLOCKS, 256, 0, stream>>>(offs, src_srt, dis,
        (const __half2*)yA, (__half2*)yB, (const float2*)emb, (__half2*)outw, alpha, 0);
    prop_kernel<<<PROP_BLOCKS, 256, 0, stream>>>(offs, src_srt, dis,
        (const __half2*)yB, (__half2*)yA, (const float2*)emb, (__half2*)outw, alpha, 1);
    prop_kernel<<<PROP_BLOCKS, 256, 0, stream>>>(offs, src_srt, dis,
        (const __half2*)yA, (__half2*)yB, (const float2*)emb, (__half2*)outw, alpha, 2);

    // ---- scoring: 64 queries per 256-thread block (16 per wave)
    score_kernel<<<NUM_QUERY / 64, 256, 0, stream>>>(q_a, q_b, (const uint4*)outw, out);
}